// Round 9
// baseline (199.012 us; speedup 1.0000x reference)
//
#include <hip/hip_runtime.h>

#define L_DIM 4096
#define B_DIM 4
#define KNN 48
#define CAP 768             // survivors ~50-60 with radix threshold; 13x margin
#define INVALID_X2 1.0e30f  // encodes mask=0: d ~ 1e15, never selectable
#define NT 256
#define CPT 16

// ---------------------------------------------------------------------------
// prep: c4 = (x, y, z, valid ? x2 : 1e30). No atomics, no side arrays.
// x2 contracted-FMA chain (matches XLA:CPU fused codegen); dot(i,i) == x2(i)
// bit-exact => D[i,i] == 0 exactly.
// ---------------------------------------------------------------------------
__global__ __launch_bounds__(256) void prep_kernel(const float* __restrict__ X,
                                                   const float* __restrict__ mask,
                                                   float4* __restrict__ c4) {
#pragma clang fp contract(off)
    int i = blockIdx.x * 256 + threadIdx.x;              // i in [0, B*L)
    const float4* X4 = (const float4*)X;                 // residue = 3 aligned float4
    float4 a = X4[3 * i];                                // ... f3(=CA x)
    float4 bb = X4[3 * i + 1];                           // f4(=CA y) f5(=CA z) ...
    float x = a.w, y = bb.x, z = bb.y;
    float x2 = __builtin_fmaf(z, z, __builtin_fmaf(y, y, x * x));
    float m = mask[i];
    c4[i] = make_float4(x, y, z, (m > 0.0f) ? x2 : INVALID_X2);
}

// ---------------------------------------------------------------------------
// main: one block per row, 256 threads, 16 candidates/thread (r5-proven base).
//  A:  d bits (correctly-rounded sqrt; selection space == output space).
//  A': n_valid wave-reduce; degenerate/invalid -> self-fill.
//  B:  2-pass radix-histogram threshold: crossing bin of top byte, then of
//      second byte within it => T = (b1,b2,0xFFFF) >= q48, T - q48 < 2^16 ulp.
//      Exact counting => certified; survivor count ~ 48 + one-2^16-bin pop.
//  C:  compact survivors (d <= T) into LDS (~50-60).
//  D:  rank-count in (d_bits, idx) order == lax.top_k tie-break, scatter.
// ---------------------------------------------------------------------------
__global__ __launch_bounds__(NT) void knn_kernel(const float4* __restrict__ c4,
                                                 const float* __restrict__ mask,
                                                 float* __restrict__ dn,
                                                 float* __restrict__ ei) {
    __shared__ unsigned long long surv[CAP];
    __shared__ unsigned hist[4][256];   // per-wave copies: 4x less atomic contention
    __shared__ unsigned wsum[4];
    __shared__ int nvw[4];
    __shared__ int cnt;
    __shared__ int bin1sh, base1sh;
    __shared__ unsigned Tsh;

    const int row = blockIdx.x;                // b*L + i
    const int b = row >> 12;
    const int i = row & (L_DIM - 1);
    const int t = threadIdx.x;
    const int w = t >> 6, lane = t & 63;

    float* dnrow = dn + (size_t)row * KNN;
    float* eirow = ei + (size_t)row * KNN;

    // invalid query row -> self-fill (block-uniform branch)
    if (!(mask[row] > 0.0f)) {
        if (t < KNN) { dnrow[t] = 0.0f; eirow[t] = (float)i; }
        return;
    }

    // ---- A: distance bits ----
    unsigned db[CPT];
    {
#pragma clang fp contract(off)
        const float4 q = c4[(size_t)b * L_DIM + i];      // q.w = x2_i (row valid)
        const float4* cb = c4 + (size_t)b * L_DIM;
#pragma unroll
        for (int c = 0; c < CPT; ++c) {
            int j = c * NT + t;
            float4 pj = cb[j];
            float dot = __builtin_fmaf(pj.z, q.z,
                        __builtin_fmaf(pj.y, q.y, pj.x * q.x));
            // fma(-2,dot,t1) == (t1 - 2*dot) bit-exactly (2*dot exact, 1 rounding)
            float d2 = fmaxf(__builtin_fmaf(-2.0f, dot, q.w + pj.w), 0.0f);
            db[c] = __float_as_uint(sqrtf(d2));
        }
    }

    // ---- A': n_valid (valid d << 1e12 << invalid ~1e15) + clear hist ----
    {
        const unsigned VTH = __float_as_uint(1.0e12f);
        int nvt = 0;
#pragma unroll
        for (int c = 0; c < CPT; ++c) nvt += (db[c] < VTH) ? 1 : 0;
#pragma unroll
        for (int s = 1; s < 64; s <<= 1) nvt += __shfl_xor(nvt, s);
        if (lane == 0) nvw[w] = nvt;
    }
    hist[0][t] = 0; hist[1][t] = 0; hist[2][t] = 0; hist[3][t] = 0;
    if (t == 0) cnt = 0;
    __syncthreads();                                   // B0
    if (nvw[0] + nvw[1] + nvw[2] + nvw[3] <= KNN) {    // degenerate batch
        if (t < KNN) { dnrow[t] = 0.0f; eirow[t] = (float)i; }
        return;
    }

    // ---- B pass1: histogram of top byte ----
#pragma unroll
    for (int c = 0; c < CPT; ++c)
        atomicAdd(&hist[w][db[c] >> 24], 1u);
    __syncthreads();                                   // B1

    // scan1: find crossing bin b1 (cum reaches KNN) + count below it
    unsigned cntb = hist[0][t] + hist[1][t] + hist[2][t] + hist[3][t];
    hist[0][t] = 0; hist[1][t] = 0; hist[2][t] = 0; hist[3][t] = 0;  // own-slot clear
    unsigned v = cntb;
#pragma unroll
    for (int s = 1; s < 64; s <<= 1) {
        unsigned o = __shfl_up(v, s);
        if (lane >= s) v += o;
    }
    if (lane == 63) wsum[w] = v;
    __syncthreads();                                   // B2
    {
        unsigned add = 0;
#pragma unroll
        for (int k = 0; k < 4; ++k) if (k < w) add += wsum[k];
        unsigned cum = v + add;                        // inclusive over 256 bins
        if (cum >= KNN && cum - cntb < KNN) {          // exactly one thread
            bin1sh = t; base1sh = (int)(cum - cntb);
        }
    }
    __syncthreads();                                   // B3
    const unsigned bin1 = (unsigned)bin1sh;
    const int base1 = base1sh;

    // ---- B pass2: histogram of byte2 within bin1 ----
#pragma unroll
    for (int c = 0; c < CPT; ++c)
        if ((db[c] >> 24) == bin1) atomicAdd(&hist[w][(db[c] >> 16) & 255u], 1u);
    __syncthreads();                                   // B4

    unsigned cntb2 = hist[0][t] + hist[1][t] + hist[2][t] + hist[3][t];
    unsigned v2 = cntb2;
#pragma unroll
    for (int s = 1; s < 64; s <<= 1) {
        unsigned o = __shfl_up(v2, s);
        if (lane >= s) v2 += o;
    }
    if (lane == 63) wsum[w] = v2;                      // old wsum consumed pre-B3
    __syncthreads();                                   // B5
    {
        unsigned add = 0;
#pragma unroll
        for (int k = 0; k < 4; ++k) if (k < w) add += wsum[k];
        unsigned tot = (unsigned)base1 + v2 + add;
        if (tot >= KNN && tot - cntb2 < KNN)           // exactly one thread
            Tsh = (bin1 << 24) | ((unsigned)t << 16) | 0xFFFFu;
    }
    __syncthreads();                                   // B6
    const unsigned T = Tsh;                            // >= q48, within 2^16 ulp

    // ---- C: compact survivors ----
#pragma unroll
    for (int c = 0; c < CPT; ++c) {
        if (db[c] <= T) {
            int pos = atomicAdd(&cnt, 1);              // LDS atomic
            if (pos < CAP) {
                unsigned j = (unsigned)(c * NT + t);
                surv[pos] = ((unsigned long long)db[c] << 32) | j;
            }
        }
    }
    __syncthreads();                                   // B7

    // ---- D: exact rank among survivors, scatter top-48 ----
    int S = cnt; if (S > CAP) S = CAP;
    for (int c2 = t; c2 < S; c2 += NT) {
        unsigned long long key = surv[c2];
        int rank = 0;
        for (int s = 0; s < S; ++s) rank += (surv[s] < key);  // broadcast reads
        if (rank < KNN) {
            dnrow[rank] = __uint_as_float((unsigned)(key >> 32));
            eirow[rank] = (float)(key & 0xFFFFFFFFULL);
        }
    }
}

extern "C" void kernel_launch(void* const* d_in, const int* in_sizes, int n_in,
                              void* d_out, int out_size, void* d_ws, size_t ws_size,
                              hipStream_t stream) {
    const float* X = (const float*)d_in[0];
    const float* mask = (const float*)d_in[1];

    float* out = (float*)d_out;
    float* dn = out;                                   // (B,L,K) D_neighbors
    float* ei = out + (size_t)B_DIM * L_DIM * KNN;     // (B,L,K) E_idx as f32

    float4* c4 = (float4*)d_ws;                        // 256 KiB scratch

    prep_kernel<<<(B_DIM * L_DIM) / 256, 256, 0, stream>>>(X, mask, c4);
    knn_kernel<<<B_DIM * L_DIM, NT, 0, stream>>>(c4, mask, dn, ei);
}

// Round 10
// 81.369 us; speedup vs baseline: 2.4458x; 2.4458x over previous
//
#include <hip/hip_runtime.h>

typedef unsigned long long u64;

#define L_DIM 4096
#define B_DIM 4
#define KNN 48
#define CAP 1024            // survivors/row ~53 expected; 19x margin
#define INVALID_X2 1.0e30f  // encodes mask=0: d^2 ~ 1e30, never selectable
#define VALID_TH 1.0e29f
#define SLACK 8u            // ulp slack on d^2 threshold covering sqrt collisions
#define NT 256
#define NW 4
#define CPT 16              // candidates per thread (NT*CPT = L_DIM)
#define ROWS 2              // query rows per block (same batch; candidates shared)

// ---------------------------------------------------------------------------
// prep: c4 = (x, y, z, valid ? x2 : 1e30). No atomics, no side arrays.
// x2 contracted-FMA chain (matches XLA:CPU fused codegen); dot(i,i) == x2(i)
// bit-exact => D[i,i] == 0 exactly.
// ---------------------------------------------------------------------------
__global__ __launch_bounds__(256) void prep_kernel(const float* __restrict__ X,
                                                   const float* __restrict__ mask,
                                                   float4* __restrict__ c4) {
#pragma clang fp contract(off)
    int i = blockIdx.x * 256 + threadIdx.x;              // i in [0, B*L)
    const float4* X4 = (const float4*)X;                 // residue = 3 aligned float4
    float4 a = X4[3 * i];                                // ... f3(=CA x)
    float4 bb = X4[3 * i + 1];                           // f4(=CA y) f5(=CA z) ...
    float x = a.w, y = bb.x, z = bb.y;
    float x2 = __builtin_fmaf(z, z, __builtin_fmaf(y, y, x * x));
    float m = mask[i];
    c4[i] = make_float4(x, y, z, (m > 0.0f) ? x2 : INVALID_X2);
}

// full ascending 64-lane bitonic sort; returns this lane's sorted value
__device__ __forceinline__ unsigned wave_sort64(unsigned sv, int lane) {
#pragma unroll
    for (int k = 2; k <= 64; k <<= 1) {
#pragma unroll
        for (int j = k >> 1; j > 0; j >>= 1) {
            unsigned o = __shfl_xor(sv, j);
            unsigned mn = min(sv, o), mx = max(sv, o);
            bool asc = ((lane & k) == 0);
            bool low = ((lane & j) == 0);
            sv = (asc == low) ? mn : mx;
        }
    }
    return sv;
}

// ---------------------------------------------------------------------------
// main: one block per 2 consecutive rows (same batch), 256 threads.
//  A:  load 16 candidates ONCE; d^2 bits for BOTH rows; per-row per-thread min;
//      candidate-validity count (pj.w) for n_valid.
//  A': block reduce n_valid; degenerate batch -> self-fill both rows.
//  B:  certified tight threshold per row = EXACT 48th-smallest of the 256
//      thread-minima (proof: <=47 elements < q48 => <=47 minima < q48 =>
//      48th minimum >= q48; tightness: 1-(1-F)^16 = 48/256 => F~1.3% => S~53).
//      Impl: per-wave bitonic sort -> composite (val,id) lists in LDS ->
//      first-48-of-each-list rank via 3 binary searches; rank-47 publishes T.
//  C:  compact survivors (d2 <= T+SLACK; SLACK covers sqrt-collision ties).
//  D1: sqrt survivors (exact keys, correctly-rounded, ~55/row).  barrier.
//  D2: rank-count in (sqrt_bits, idx) order == lax.top_k tie-break, scatter;
//      invalid row -> self-fill. All cross-stage LDS deps barriered.
// ---------------------------------------------------------------------------
__global__ __launch_bounds__(NT) void knn_kernel(const float4* __restrict__ c4,
                                                 float* __restrict__ dn,
                                                 float* __restrict__ ei) {
    __shared__ u64 smin[ROWS][NT];      // 4 KB: sorted minima (composite keys)
    __shared__ u64 surv[ROWS][CAP];     // 16 KB
    __shared__ int nvw[NW];
    __shared__ int cnt[ROWS];
    __shared__ unsigned Tsh[ROWS];

    const int row0 = blockIdx.x * ROWS;
    const int b = row0 >> 12;
    const int i0 = row0 & (L_DIM - 1);
    const int t = threadIdx.x;
    const int w = t >> 6, lane = t & 63;

    const float4* cb = c4 + (size_t)b * L_DIM;
    const float4 q0 = cb[i0];                  // broadcast loads
    const float4 q1 = cb[i0 + 1];
    const bool v0 = (q0.w < VALID_TH), v1 = (q1.w < VALID_TH);

    // ---- A: 16 candidates/thread, d^2 for both rows + validity count ----
    unsigned d20[CPT], d21[CPT];
    unsigned rmin0 = 0xFFFFFFFFu, rmin1 = 0xFFFFFFFFu;
    int nvt = 0;
    {
#pragma clang fp contract(off)
#pragma unroll
        for (int c = 0; c < CPT; ++c) {
            int j = c * NT + t;
            float4 pj = cb[j];
            nvt += (pj.w < VALID_TH) ? 1 : 0;
            float dota = __builtin_fmaf(pj.z, q0.z,
                         __builtin_fmaf(pj.y, q0.y, pj.x * q0.x));
            float dotb = __builtin_fmaf(pj.z, q1.z,
                         __builtin_fmaf(pj.y, q1.y, pj.x * q1.x));
            // fma(-2,dot,t1) == (t1 - 2*dot) bit-exactly (2*dot exact, 1 rounding)
            float d2a = fmaxf(__builtin_fmaf(-2.0f, dota, q0.w + pj.w), 0.0f);
            float d2b = fmaxf(__builtin_fmaf(-2.0f, dotb, q1.w + pj.w), 0.0f);
            d20[c] = __float_as_uint(d2a);
            d21[c] = __float_as_uint(d2b);
            rmin0 = min(rmin0, d20[c]);
            rmin1 = min(rmin1, d21[c]);
        }
    }

    // ---- A': n_valid block reduce; degen -> self-fill both rows ----
#pragma unroll
    for (int s = 1; s < 64; s <<= 1) nvt += __shfl_xor(nvt, s);
    if (lane == 0) nvw[w] = nvt;
    if (t < ROWS) cnt[t] = 0;
    __syncthreads();
    if (nvw[0] + nvw[1] + nvw[2] + nvw[3] <= KNN) {
        if (w < ROWS && lane < KNN) {
            dn[(size_t)(row0 + w) * KNN + lane] = 0.0f;
            ei[(size_t)(row0 + w) * KNN + lane] = (float)(i0 + w);
        }
        return;
    }

    // ---- B: sorted minima lists (composite (value<<32)|uniqueid) ----
    {
        unsigned sv0 = wave_sort64(rmin0, lane);
        unsigned sv1 = wave_sort64(rmin1, lane);
        smin[0][t] = ((u64)sv0 << 32) | (unsigned)t;   // ascending within wave seg
        smin[1][t] = ((u64)sv1 << 32) | (unsigned)t;
    }
    __syncthreads();

    // rank-search: candidates = first KNN of each wave's sorted list, both rows
    for (int tau = t; tau < ROWS * NW * KNN; tau += NT) {
        int r = tau / (NW * KNN);
        int rest = tau - r * (NW * KNN);
        int ww = rest / KNN, p = rest - ww * KNN;
        u64 key = smin[r][ww * 64 + p];
        int grank = p;                          // elements before it in own list
#pragma unroll
        for (int w2 = 0; w2 < NW; ++w2) {
            if (w2 == ww) continue;
            const u64* arr = &smin[r][w2 * 64];
            int lo = 0;
#pragma unroll
            for (int s = 32; s >= 1; s >>= 1)
                if (arr[lo + s - 1] < key) lo += s;
            lo += (arr[lo] < key) ? 1 : 0;      // lo in [0,64] = count < key
            grank += lo;
        }
        if (grank == KNN - 1) Tsh[r] = (unsigned)(key >> 32);  // unique publisher
    }
    __syncthreads();
    const unsigned Tp0 = v0 ? (Tsh[0] + SLACK) : 0u;   // invalid row: no survivors
    const unsigned Tp1 = v1 ? (Tsh[1] + SLACK) : 0u;

    // ---- C: compact survivors per row ----
#pragma unroll
    for (int c = 0; c < CPT; ++c) {
        unsigned j = (unsigned)(c * NT + t);
        if (d20[c] <= Tp0) {
            int pos = atomicAdd(&cnt[0], 1);
            if (pos < CAP) surv[0][pos] = ((u64)d20[c] << 32) | j;
        }
        if (d21[c] <= Tp1) {
            int pos = atomicAdd(&cnt[1], 1);
            if (pos < CAP) surv[1][pos] = ((u64)d21[c] << 32) | j;
        }
    }
    __syncthreads();

    // ---- D1: exact keys (correctly-rounded sqrt), block-wide, both rows ----
    {
        int S0 = cnt[0]; if (S0 > CAP) S0 = CAP;
        int S1 = cnt[1]; if (S1 > CAP) S1 = CAP;
        for (int c = t; c < S0; c += NT) {
            u64 key = surv[0][c];
            float d = sqrtf(__uint_as_float((unsigned)(key >> 32)));
            surv[0][c] = ((u64)__float_as_uint(d) << 32) | (key & 0xFFFFFFFFULL);
        }
        for (int c = t; c < S1; c += NT) {
            u64 key = surv[1][c];
            float d = sqrtf(__uint_as_float((unsigned)(key >> 32)));
            surv[1][c] = ((u64)__float_as_uint(d) << 32) | (key & 0xFFFFFFFFULL);
        }
    }
    __syncthreads();

    // ---- D2: per row, block-wide exact rank + scatter (or self-fill) ----
#pragma unroll
    for (int r = 0; r < ROWS; ++r) {
        const bool vr = r ? v1 : v0;
        float* dnrow = dn + (size_t)(row0 + r) * KNN;
        float* eirow = ei + (size_t)(row0 + r) * KNN;
        if (!vr) {                              // block-uniform branch
            if (t < KNN) { dnrow[t] = 0.0f; eirow[t] = (float)(i0 + r); }
        } else {
            int S = cnt[r]; if (S > CAP) S = CAP;
            for (int c = t; c < S; c += NT) {
                u64 key = surv[r][c];
                int rank = 0;
                for (int s = 0; s < S; ++s) rank += (surv[r][s] < key);  // broadcast
                if (rank < KNN) {
                    dnrow[rank] = __uint_as_float((unsigned)(key >> 32));
                    eirow[rank] = (float)(key & 0xFFFFFFFFULL);
                }
            }
        }
    }
}

extern "C" void kernel_launch(void* const* d_in, const int* in_sizes, int n_in,
                              void* d_out, int out_size, void* d_ws, size_t ws_size,
                              hipStream_t stream) {
    const float* X = (const float*)d_in[0];
    const float* mask = (const float*)d_in[1];

    float* out = (float*)d_out;
    float* dn = out;                                   // (B,L,K) D_neighbors
    float* ei = out + (size_t)B_DIM * L_DIM * KNN;     // (B,L,K) E_idx as f32

    float4* c4 = (float4*)d_ws;                        // 256 KiB scratch

    prep_kernel<<<(B_DIM * L_DIM) / 256, 256, 0, stream>>>(X, mask, c4);
    knn_kernel<<<(B_DIM * L_DIM) / ROWS, NT, 0, stream>>>(c4, dn, ei);
}